// Round 1
// baseline (416.039 us; speedup 1.0000x reference)
//
#include <hip/hip_runtime.h>
#include <stdint.h>

// DetectionBaseline: SSD post-process.
// Inputs: locs [16,1280,4] f32, scores [16,1280,21] f32, anchors [1280,4] f32, top_k (=200, hardcoded).
// Output (flat f32): boxes [16,200,4] | labels [16,200] (as float) | scores [16,200].
// ws: uint64 keys [16][20][200] = 512000 bytes.

#define A_N     1280
#define CF      20
#define NC      21
#define B_N     16
#define TOPK    200
#define THREADS 256
#define SORT_N  2048
#define FIN_N   4096

static __device__ __forceinline__ uint64_t pack_key(float sc, uint32_t idx) {
    // scores are positive -> float bits monotone. ~bits => ascending key = descending score;
    // low 32 bits = index => ties break toward smaller index (matches stable argsort / lax.top_k).
    return ((uint64_t)(uint32_t)(~__float_as_uint(sc)) << 32) | (uint64_t)idx;
}

__global__ __launch_bounds__(THREADS)
void nms_kernel(const float* __restrict__ locs,
                const float* __restrict__ scores,
                const float* __restrict__ anchors,
                uint64_t* __restrict__ ws_keys)
{
    __shared__ float4        sbox[A_N];
    __shared__ float         sarea[A_N];
    __shared__ uint64_t      skeys[SORT_N];
    __shared__ unsigned char ssup[A_N];
    __shared__ int           swin[THREADS / 64];
    __shared__ int           sbcast;

    const int blk = blockIdx.x;
    const int b   = blk / CF;
    const int c   = blk % CF + 1;   // class channel 1..20
    const int t   = threadIdx.x;

    // ---- decode boxes, softmax class score, build sort keys ----
    for (int i = 0; i < A_N / THREADS; ++i) {
        const int a = t + i * THREADS;
        const float4 lc = ((const float4*)locs)[(size_t)b * A_N + a];
        const float4 an = ((const float4*)anchors)[a];
        const float cx = lc.x * an.z / 10.0f + an.x;
        const float cy = lc.y * an.w / 10.0f + an.y;
        const float w  = expf(lc.z / 5.0f) * an.z;
        const float h  = expf(lc.w / 5.0f) * an.w;
        float4 bx;
        bx.x = cx - w / 2.0f; bx.y = cy - h / 2.0f;
        bx.z = cx + w / 2.0f; bx.w = cy + h / 2.0f;
        sbox[a]  = bx;
        sarea[a] = (bx.z - bx.x) * (bx.w - bx.y);  // match ref: area from box coords

        const float* sp = scores + ((size_t)b * A_N + a) * NC;
        float m = sp[0];
        #pragma unroll
        for (int k = 1; k < NC; ++k) m = fmaxf(m, sp[k]);
        float sum = 0.0f;
        #pragma unroll
        for (int k = 0; k < NC; ++k) sum += expf(sp[k] - m);
        const float sc = expf(sp[c] - m) / sum;
        // invalid (<= MIN_SCORE) anchors are never active and never kept -> drop from sort
        skeys[a] = (sc > 0.01f) ? pack_key(sc, (uint32_t)a) : ~0ull;
        ssup[a]  = 0;
    }
    for (int i = A_N + t; i < SORT_N; i += THREADS) skeys[i] = ~0ull;

    // ---- bitonic sort ascending (= descending score, ties -> smaller anchor idx) ----
    for (int kk = 2; kk <= SORT_N; kk <<= 1)
        for (int j = kk >> 1; j > 0; j >>= 1) {
            __syncthreads();
            for (int i = t; i < SORT_N; i += THREADS) {
                const int ixj = i ^ j;
                if (ixj > i) {
                    const uint64_t a0 = skeys[i], a1 = skeys[ixj];
                    const bool up = ((i & kk) == 0);
                    if ((a0 > a1) == up) { skeys[i] = a1; skeys[ixj] = a0; }
                }
            }
        }
    __syncthreads();

    uint64_t* const out  = ws_keys + ((size_t)b * CF + (c - 1)) * TOPK;
    const uint32_t  base = (uint32_t)(c - 1) * A_N;

    // ---- sequential NMS with active-rank skip-ahead (exactly equivalent to ref scan) ----
    int r = 0, nkept = 0;
    while (r < A_N && nkept < TOPK) {
        // find first rank q >= r that is active under the current suppress state
        const int q = r + t;
        bool ok = false;
        if (q < SORT_N) {
            const uint64_t k = skeys[q];
            if (k != ~0ull) ok = (ssup[(uint32_t)k] == 0);
        }
        const unsigned long long ball = __ballot(ok);
        const int wv = t >> 6;
        if ((t & 63) == 0)
            swin[wv] = ball ? (wv * 64 + (__ffsll(ball) - 1)) : 0x7FFFFFFF;
        __syncthreads();
        if (t == 0) {
            int mn = swin[0];
            #pragma unroll
            for (int wvi = 1; wvi < THREADS / 64; ++wvi) mn = min(mn, swin[wvi]);
            sbcast = mn;
        }
        __syncthreads();
        const int off = sbcast;
        if (off == 0x7FFFFFFF) {
            const bool done = (skeys[r] == ~0ull);  // sorted: ~0 at window start => rest invalid
            r += THREADS;
            if (done) break;
            continue;
        }
        const int rp = r + off;
        const uint64_t kk2 = skeys[rp];
        const uint32_t ai  = (uint32_t)kk2;
        if (t == 0) out[nkept] = (kk2 & 0xFFFFFFFF00000000ull) | (uint64_t)(base + ai);
        ++nkept;  // uniform across block

        // suppress everything with IoU > 0.45 vs box[ai] (includes ai itself; cleared below)
        const float4 bi    = sbox[ai];
        const float  areai = sarea[ai];
        #pragma unroll
        for (int i = 0; i < A_N / THREADS; ++i) {
            const int a2 = t + i * THREADS;
            const float4 bj = sbox[a2];
            const float lx = fmaxf(bi.x, bj.x);
            const float ly = fmaxf(bi.y, bj.y);
            const float rx = fminf(bi.z, bj.z);
            const float ry = fminf(bi.w, bj.w);
            const float wx = fmaxf(rx - lx, 0.0f);
            const float wy = fmaxf(ry - ly, 0.0f);
            const float inter = wx * wy;
            const float uni   = areai + sarea[a2] - inter;
            if (inter / uni > 0.45f) ssup[a2] = 1;
        }
        __syncthreads();
        if (t == 0) ssup[ai] = 0;   // ref clears the active index after OR-ing its row
        r = rp + 1;
        __syncthreads();
    }
    // pad unused per-class slots
    for (int i = nkept + t; i < TOPK; i += THREADS) out[i] = ~0ull;
}

__global__ __launch_bounds__(THREADS)
void topk_kernel(const float* __restrict__ locs,
                 const float* __restrict__ anchors,
                 const uint64_t* __restrict__ ws_keys,
                 float* __restrict__ out)
{
    __shared__ uint64_t skeys[FIN_N];
    const int b = blockIdx.x;
    const int t = threadIdx.x;
    const uint64_t* const in = ws_keys + (size_t)b * CF * TOPK;
    for (int i = t; i < FIN_N; i += THREADS)
        skeys[i] = (i < CF * TOPK) ? in[i] : ~0ull;

    for (int kk = 2; kk <= FIN_N; kk <<= 1)
        for (int j = kk >> 1; j > 0; j >>= 1) {
            __syncthreads();
            for (int i = t; i < FIN_N; i += THREADS) {
                const int ixj = i ^ j;
                if (ixj > i) {
                    const uint64_t a0 = skeys[i], a1 = skeys[ixj];
                    const bool up = ((i & kk) == 0);
                    if ((a0 > a1) == up) { skeys[i] = a1; skeys[ixj] = a0; }
                }
            }
        }
    __syncthreads();

    if (t < TOPK) {
        const uint64_t k = skeys[t];
        float* const boxes_out  = out;                              // [B][TOPK][4]
        float* const labels_out = out + (size_t)B_N * TOPK * 4;     // [B][TOPK]
        float* const scores_out = out + (size_t)B_N * TOPK * 5;     // [B][TOPK]
        const size_t s = (size_t)b * TOPK + t;
        if (k == ~0ull) {
            boxes_out[s * 4 + 0] = 0.0f;
            boxes_out[s * 4 + 1] = 0.0f;
            boxes_out[s * 4 + 2] = 0.0f;
            boxes_out[s * 4 + 3] = 0.0f;
            labels_out[s] = 0.0f;
            scores_out[s] = 0.0f;
        } else {
            const uint32_t flat = (uint32_t)k;
            const int cls = flat / A_N;          // 0..19
            const int a   = flat - cls * A_N;
            const float sc = __uint_as_float(~(uint32_t)(k >> 32));
            const float4 lc = ((const float4*)locs)[(size_t)b * A_N + a];
            const float4 an = ((const float4*)anchors)[a];
            const float cx = lc.x * an.z / 10.0f + an.x;
            const float cy = lc.y * an.w / 10.0f + an.y;
            const float w  = expf(lc.z / 5.0f) * an.z;
            const float h  = expf(lc.w / 5.0f) * an.w;
            boxes_out[s * 4 + 0] = cx - w / 2.0f;
            boxes_out[s * 4 + 1] = cy - h / 2.0f;
            boxes_out[s * 4 + 2] = cx + w / 2.0f;
            boxes_out[s * 4 + 3] = cy + h / 2.0f;
            labels_out[s] = (float)(cls + 1);
            scores_out[s] = sc;
        }
    }
}

extern "C" void kernel_launch(void* const* d_in, const int* in_sizes, int n_in,
                              void* d_out, int out_size, void* d_ws, size_t ws_size,
                              hipStream_t stream) {
    const float* locs    = (const float*)d_in[0];
    const float* scores  = (const float*)d_in[1];
    const float* anchors = (const float*)d_in[2];
    // d_in[3] = top_k (always 200 per setup_inputs; output buffer size is fixed accordingly)
    uint64_t* ws  = (uint64_t*)d_ws;       // needs 16*20*200*8 = 512000 bytes
    float*    out = (float*)d_out;         // 19200 floats

    hipLaunchKernelGGL(nms_kernel,  dim3(B_N * CF), dim3(THREADS), 0, stream,
                       locs, scores, anchors, ws);
    hipLaunchKernelGGL(topk_kernel, dim3(B_N),      dim3(THREADS), 0, stream,
                       locs, anchors, ws, out);
}

// Round 2
// 226.600 us; speedup vs baseline: 1.8360x; 1.8360x over previous
//
#include <hip/hip_runtime.h>
#include <stdint.h>

// DetectionBaseline: SSD post-process, argmax-fused NMS (no sort) + merge-tree top-k.
// Inputs: locs [16,1280,4] f32, scores [16,1280,21] f32, anchors [1280,4] f32, top_k(=200).
// Output (flat f32): boxes [16,200,4] | labels [16,200] (as float) | scores [16,200].
// ws: uint64 keys [16][20][200] = 512000 bytes (per-class kept lists, ascending key = desc score).

#define A_N     1280
#define CF      20
#define NC      21
#define B_N     16
#define TOPK    200
#define THREADS 256
#define CPT     (A_N / THREADS)   // 5 candidates per thread

static __device__ __forceinline__ uint64_t pack_key(float sc, uint32_t idx) {
    // softmax scores are positive -> float bits monotone. ~bits => ascending key = descending
    // score; low 32 bits = index => ties break toward smaller index (stable argsort / top_k).
    return ((uint64_t)(uint32_t)(~__float_as_uint(sc)) << 32) | (uint64_t)idx;
}

__global__ __launch_bounds__(THREADS)
void nms_kernel(const float* __restrict__ locs,
                const float* __restrict__ scores,
                const float* __restrict__ anchors,
                uint64_t* __restrict__ ws_keys)
{
    __shared__ float4   sbox[A_N];        // winner-box broadcast lookups (20 KB)
    __shared__ uint64_t spart[2][4];      // ping-pong per-wave partial mins

    const int blk = blockIdx.x;
    const int b   = blk / CF;
    const int c   = blk % CF + 1;         // class channel 1..20
    const int t   = threadIdx.x;
    const int wid = t >> 6;

    // ---- decode boxes + softmax + key build; candidates register-resident ----
    float4   bx[CPT];
    float    ar[CPT];
    uint64_t key[CPT];
    uint64_t mloc = ~0ull;

    #pragma unroll
    for (int i = 0; i < CPT; ++i) {
        const int a = t + i * THREADS;
        const float4 lc = ((const float4*)locs)[(size_t)b * A_N + a];
        const float4 an = ((const float4*)anchors)[a];
        const float cx = lc.x * an.z / 10.0f + an.x;
        const float cy = lc.y * an.w / 10.0f + an.y;
        const float w  = expf(lc.z / 5.0f) * an.z;
        const float h  = expf(lc.w / 5.0f) * an.w;
        float4 v;
        v.x = cx - w / 2.0f; v.y = cy - h / 2.0f;
        v.z = cx + w / 2.0f; v.w = cy + h / 2.0f;
        sbox[a] = v;
        bx[i]   = v;
        ar[i]   = (v.z - v.x) * (v.w - v.y);   // ref: area from decoded box coords

        const float* sp = scores + ((size_t)b * A_N + a) * NC;
        float m = sp[0];
        #pragma unroll
        for (int k = 1; k < NC; ++k) m = fmaxf(m, sp[k]);
        float sum = 0.0f;
        #pragma unroll
        for (int k = 0; k < NC; ++k) sum += expf(sp[k] - m);
        const float sc = expf(sp[c] - m) / sum;
        key[i] = (sc > 0.01f) ? pack_key(sc, (uint32_t)a) : ~0ull;  // invalid never active/kept
        mloc   = key[i] < mloc ? key[i] : mloc;
    }
    __syncthreads();   // sbox ready

    uint64_t* const out  = ws_keys + ((size_t)b * CF + (c - 1)) * TOPK;
    const uint32_t  base = (uint32_t)(c - 1) * A_N;

    // ---- argmax-fused NMS: next active in score order == min alive key.
    //      Winner self-suppresses (IoU with itself = 1 > 0.45); IoU symmetry guarantees a
    //      later active box can never suppress an earlier winner (round-1 verified). ----
    int kept = 0;
    int p    = 0;
    while (kept < TOPK) {
        // wave min-reduce of per-thread alive min
        uint64_t m = mloc;
        #pragma unroll
        for (int off = 32; off; off >>= 1) {
            const uint64_t o = (uint64_t)__shfl_xor((unsigned long long)m, off, 64);
            m = o < m ? o : m;
        }
        if ((t & 63) == 0) spart[p][wid] = m;
        __syncthreads();                         // single barrier per step (ping-pong buffers)
        const uint64_t m0 = spart[p][0], m1 = spart[p][1];
        const uint64_t m2 = spart[p][2], m3 = spart[p][3];
        uint64_t ma = m0 < m1 ? m0 : m1;
        uint64_t mb = m2 < m3 ? m2 : m3;
        m = ma < mb ? ma : mb;
        p ^= 1;

        if (m == ~0ull) break;                   // no alive valid candidates left
        const uint32_t ai = (uint32_t)m;         // anchor idx 0..1279
        if (t == 0) out[kept] = (m & 0xFFFFFFFF00000000ull) | (uint64_t)(base + ai);
        ++kept;

        const float4 bw    = sbox[ai];           // uniform addr -> LDS broadcast
        const float  warea = (bw.z - bw.x) * (bw.w - bw.y);

        // kill overlaps; fold next-step per-thread min into the same pass
        mloc = ~0ull;
        #pragma unroll
        for (int i = 0; i < CPT; ++i) {
            const float lx = fmaxf(bw.x, bx[i].x);
            const float ly = fmaxf(bw.y, bx[i].y);
            const float rx = fminf(bw.z, bx[i].z);
            const float ry = fminf(bw.w, bx[i].w);
            const float wx = fmaxf(rx - lx, 0.0f);
            const float wy = fmaxf(ry - ly, 0.0f);
            const float inter = wx * wy;
            const float uni   = warea + ar[i] - inter;
            key[i] = (inter / uni > 0.45f) ? ~0ull : key[i];   // ref-exact division + compare
            mloc   = key[i] < mloc ? key[i] : mloc;
        }
    }
    // pad unused per-class slots
    for (int i = kept + t; i < TOPK; i += THREADS) out[i] = ~0ull;
}

// Per batch: top-200 of 20 sorted (ascending-key) 200-lists via truncated pairwise merges.
// top200(U lists) == top200(top200(A) U top200(B)) pairwise -> 5-level merge tree.
// Each merge: bitonic lower-half extraction d[i]=min(a[i],b[255-i]) (contains the 256
// smallest, bitonic) then 8-pass bitonic merge -> sorted ascending 256.
__global__ __launch_bounds__(THREADS)
void merge_kernel(const float* __restrict__ locs,
                  const float* __restrict__ anchors,
                  const uint64_t* __restrict__ ws_keys,
                  float* __restrict__ out)
{
    __shared__ uint64_t Abuf[20][256];   // 40 KB
    __shared__ uint64_t Bbuf[10][256];   // 20 KB

    const int b = blockIdx.x;
    const int t = threadIdx.x;
    const uint64_t* const in = ws_keys + (size_t)b * CF * TOPK;

    // load 20 lists, pad 200 -> 256 with ~0
    for (int e = t; e < CF * 256; e += THREADS) {
        const int c = e >> 8, i = e & 255;
        Abuf[c][i] = (i < TOPK) ? in[c * TOPK + i] : ~0ull;
    }

    uint64_t (*src)[256] = Abuf;
    uint64_t (*dst)[256] = Bbuf;
    int n = CF;
    while (n > 1) {
        const int  nm    = n >> 1;
        const bool carry = (n & 1) != 0;
        __syncthreads();
        // extraction pass (+ carry copy)
        for (int e = t; e < nm * 256; e += THREADS) {
            const int mm = e >> 8, i = e & 255;
            const uint64_t x = src[2 * mm][i];
            const uint64_t y = src[2 * mm + 1][255 - i];
            dst[mm][i] = x < y ? x : y;
        }
        if (carry)
            for (int i = t; i < 256; i += THREADS) dst[nm][i] = src[n - 1][i];
        // bitonic merge passes, all merges of the level in parallel
        for (int j = 128; j; j >>= 1) {
            __syncthreads();
            for (int pp = t; pp < nm * 128; pp += THREADS) {
                const int mm = pp >> 7, q = pp & 127;
                const int i  = ((q & ~(j - 1)) << 1) | (q & (j - 1));
                const uint64_t x = dst[mm][i], y = dst[mm][i + j];
                if (y < x) { dst[mm][i] = y; dst[mm][i + j] = x; }
            }
        }
        uint64_t (*tmp)[256] = src; src = dst; dst = tmp;
        n = nm + (carry ? 1 : 0);
    }
    __syncthreads();
    // result ascending in src[0][0..255]; first 200 are the detections (score-descending)

    if (t < TOPK) {
        const uint64_t k = src[0][t];
        float* const boxes_out  = out;                           // [B][TOPK][4]
        float* const labels_out = out + (size_t)B_N * TOPK * 4;  // [B][TOPK]
        float* const scores_out = out + (size_t)B_N * TOPK * 5;  // [B][TOPK]
        const size_t s = (size_t)b * TOPK + t;
        if (k == ~0ull) {
            boxes_out[s * 4 + 0] = 0.0f;
            boxes_out[s * 4 + 1] = 0.0f;
            boxes_out[s * 4 + 2] = 0.0f;
            boxes_out[s * 4 + 3] = 0.0f;
            labels_out[s] = 0.0f;
            scores_out[s] = 0.0f;
        } else {
            const uint32_t flat = (uint32_t)k;
            const int cls = flat / A_N;          // 0..19
            const int a   = flat - cls * A_N;
            const float sc = __uint_as_float(~(uint32_t)(k >> 32));
            const float4 lc = ((const float4*)locs)[(size_t)b * A_N + a];
            const float4 an = ((const float4*)anchors)[a];
            const float cx = lc.x * an.z / 10.0f + an.x;
            const float cy = lc.y * an.w / 10.0f + an.y;
            const float w  = expf(lc.z / 5.0f) * an.z;
            const float h  = expf(lc.w / 5.0f) * an.w;
            boxes_out[s * 4 + 0] = cx - w / 2.0f;
            boxes_out[s * 4 + 1] = cy - h / 2.0f;
            boxes_out[s * 4 + 2] = cx + w / 2.0f;
            boxes_out[s * 4 + 3] = cy + h / 2.0f;
            labels_out[s] = (float)(cls + 1);
            scores_out[s] = sc;
        }
    }
}

extern "C" void kernel_launch(void* const* d_in, const int* in_sizes, int n_in,
                              void* d_out, int out_size, void* d_ws, size_t ws_size,
                              hipStream_t stream) {
    const float* locs    = (const float*)d_in[0];
    const float* scores  = (const float*)d_in[1];
    const float* anchors = (const float*)d_in[2];
    // d_in[3] = top_k (always 200 per setup_inputs)
    uint64_t* ws  = (uint64_t*)d_ws;     // 512000 bytes used
    float*    outp = (float*)d_out;      // 19200 floats

    hipLaunchKernelGGL(nms_kernel,   dim3(B_N * CF), dim3(THREADS), 0, stream,
                       locs, scores, anchors, ws);
    hipLaunchKernelGGL(merge_kernel, dim3(B_N),      dim3(THREADS), 0, stream,
                       locs, anchors, ws, outp);
}